// Round 9
// baseline (131.741 us; speedup 1.0000x reference)
//
#include <hip/hip_runtime.h>
#include <math.h>

// SSIM char-matcher: img (1,1,1024,768) f32, chars (95,1,16,6) f32 -> argmax idx [64][128] int32
// H=16, W=6, WIN=3, tiles T=8192 (64 rows x 128 cols), refs R=95 (pad to 96)
// Grid: 256 blocks = (64 rows) x (4 col-groups of 32 tiles); all 96 refs in-block.
// 768 threads = 12 waves; wave owns 8 px -> 3 waves/SIMD.

static constexpr float kC1 = 1.0e-4f;   // 0.01^2
static constexpr float kC2 = 9.0e-4f;   // 0.03^2

struct KF { float k[9]; };

__device__ __forceinline__ int refl(int x, int n) {
  if (x < 0) return -x;
  if (x >= n) return 2 * n - 2 - x;
  return x;
}

// ---------------- Kernel 1: per-ref precompute ----------------
// refdata: per hw a chunk of 96 rows x 12 floats (4608 B, contiguous).
// Logical ref r (0..95) stored at physical row rp = r/6 + 16*(r%6)
// (lane rthr reads ref rthr*6+j at row rthr+16j -> stride 48 B, 2-way banks = ~free).
// Row: f0..8 = 2*k[k]*Rp[k] (DOUBLED), f9 = 2*mu_r (DOUBLED),
// f10 = mu_r^2 + C1, f11 = sig_r + C2.  r=95 is padding (never argmax'd).
__global__ __launch_bounds__(128) void refprep_kernel(
    const float* __restrict__ chars, float* __restrict__ refdata,
    float* __restrict__ densR, KF kf) {
  const int hw = blockIdx.x;   // 0..95
  const int r = threadIdx.x;   // 0..127
  if (r >= 96) return;
  const int rp = r / 6 + 16 * (r % 6);
  float* row = refdata + ((size_t)hw * 96 + rp) * 12;
  const int h = hw / 6, w = hw % 6;
  if (r < 95) {
    const float* cb = chars + r * 96;
    float mu = 0.f, ex2 = 0.f;
    float wrv[9];
#pragma unroll
    for (int i = 0; i < 3; ++i) {
      const int hh = refl(h + i - 1, 16);
#pragma unroll
      for (int j = 0; j < 3; ++j) {
        const int ww = refl(w + j - 1, 6);
        const float p = cb[hh * 6 + ww];
        const float kv = kf.k[i * 3 + j];
        wrv[i * 3 + j] = 2.0f * kv * p;
        mu += kv * p;
        ex2 += kv * p * p;
      }
    }
    const float sig = ex2 - mu * mu;
#pragma unroll
    for (int k = 0; k < 9; ++k) row[k] = wrv[k];
    row[9]  = 2.0f * mu;
    row[10] = mu * mu + kC1;
    row[11] = sig + kC2;
  } else {
#pragma unroll
    for (int k = 0; k < 9; ++k) row[k] = 0.f;
    row[9]  = 0.f;
    row[10] = kC1;
    row[11] = kC2;
  }
  if (hw == 0) {
    if (r < 95) {
      float s = 0.f;
      for (int i = 0; i < 96; ++i) s += chars[r * 96 + i];
      densR[r] = s * (1.0f / 96.0f);
    } else {
      densR[r] = 0.f;
    }
  }
}

// ---- async global->LDS staging of one 1152-float (4608 B) ref chunk ----
// 4 x (64 lanes x 16B) + 2 x (64 lanes x 4B); counts 6 on vmcnt.
__device__ __forceinline__ void stage_px(const float* __restrict__ src,
                                         float* dst, int lane) {
  const uintptr_t gs = (uintptr_t)src;
  const uintptr_t ls = (uintptr_t)dst;
#define G_(off) ((const __attribute__((address_space(1))) void*)(gs + (off)))
#define L_(off) ((__attribute__((address_space(3))) void*)(uint32_t)(ls + (off)))
  __builtin_amdgcn_global_load_lds(G_(0    + lane * 16), L_(0),    16, 0, 0);
  __builtin_amdgcn_global_load_lds(G_(1024 + lane * 16), L_(1024), 16, 0, 0);
  __builtin_amdgcn_global_load_lds(G_(2048 + lane * 16), L_(2048), 16, 0, 0);
  __builtin_amdgcn_global_load_lds(G_(3072 + lane * 16), L_(3072), 16, 0, 0);
  __builtin_amdgcn_global_load_lds(G_(4096 + lane * 4),  L_(4096), 4, 0, 0);
  __builtin_amdgcn_global_load_lds(G_(4352 + lane * 4),  L_(4352), 4, 0, 0);
#undef G_
#undef L_
}

// ---------------- Kernel 2: main SSIM + argmax ----------------
// 256 blocks x 768 threads (12 waves). Block = 32 tiles x 96 refs x 96 px.
// Wave w owns px [8w, 8w+8). lane = tthr(4 x 8 tiles) x rthr(16 x 6 refs)
// -> 48 el/thread. Wave-private double-buffered ref chunk, zero main-loop
// barriers, counted vmcnt(6). Score via raw v_rcp (1-ulp; passed absmax 0).
//
// Register-budget control (R3-R8 evidence): the allocator's occupancy
// heuristic picks a VGPR tier WITHOUT LDS awareness — for 768-thr blocks it
// squeezed to 84 (6 waves/EU "2 blocks/CU" tier) and spilled ~56 regs
// (R8: 205 MB FETCH / 360 MB WRITE of scratch, 131 us). LDS (154 KB) caps
// residency at 1 block/CU = 3 waves/SIMD, so the correct budget is
// floor(512/3)=170. amdgpu_num_vgpr(168) pins the allocation budget
// directly (not an occupancy hint); pressure ~145 fits -> no spills.
__global__ __launch_bounds__(768)
__attribute__((amdgpu_num_vgpr(168)))
void ssim_main_kernel(
    const float* __restrict__ img, const float* __restrict__ refdata,
    const float* __restrict__ densR, int* __restrict__ out, KF kf) {
  // [0:4608) padT [144][32] | [4608:10752) statT [2][96][32] |
  // [10752:38400) refbuf 12 waves x 2 x 1152. Overlay after loop: sb[12][32][97].
  __shared__ float smem[38400];
  __shared__ float densT[32];
  float* padT = smem;
  float* statT = smem + 4608;

  const int tid = threadIdx.x;
  const int w = tid >> 6;          // wave 0..11
  const int lane = tid & 63;
  const int tthr = lane >> 4;      // 0..3  -> 8 tiles each
  const int rthr = lane & 15;      // 0..15 -> 6 refs each
  const int tl0 = tthr * 8;
  const int blk = blockIdx.x;
  const int row0 = blk >> 2;           // tile-row 0..63
  const int c0 = (blk & 3) * 32;       // tile-col base
  const int hwBase = w * 8;            // wave = 8 px (may start mid-row)
  float* rbuf = smem + 10752 + w * 2304;   // wave-private 2 x 1152

  // Issue px0 staging immediately; the first __syncthreads drains lgkm/vm.
  stage_px(refdata + (size_t)hwBase * 1152, rbuf, lane);

  // Phase A: reflect-padded tiles, transposed: padT[c(0..143)][tile(0..31)]
  for (int idx = tid; idx < 4608; idx += 768) {
    const int c = idx >> 5, tl = idx & 31;
    const int ph = c >> 3, pw = c & 7;
    const int h = refl(ph - 1, 16), ww = refl(pw - 1, 6);
    padT[idx] = img[(row0 * 16 + h) * 768 + (c0 + tl) * 6 + ww];
  }
  __syncthreads();

  if (tid < 32) {
    float s = 0.f;
    for (int h = 0; h < 16; ++h)
      for (int ww = 0; ww < 6; ++ww)
        s += padT[((h + 1) * 8 + (ww + 1)) * 32 + tid];
    densT[tid] = s * (1.0f / 96.0f);
  }
  // Phase B: per-(hw, tile) stats: mu, sig
  for (int idx = tid; idx < 3072; idx += 768) {
    const int hw = idx >> 5, tl = idx & 31;
    const int h = hw / 6, ww = hw % 6;
    float mu = 0.f, ex2 = 0.f;
#pragma unroll
    for (int i = 0; i < 3; ++i)
#pragma unroll
      for (int j = 0; j < 3; ++j) {
        const float p = padT[((h + i) * 8 + (ww + j)) * 32 + tl];
        const float kv = kf.k[i * 3 + j];
        mu += kv * p;
        ex2 += kv * p * p;
      }
    statT[idx] = mu;
    statT[3072 + idx] = ex2 - mu * mu;
  }
  __syncthreads();

  float score[8][6];
#pragma unroll
  for (int i = 0; i < 8; ++i)
#pragma unroll
    for (int j = 0; j < 6; ++j) score[i][j] = 0.f;

  // Incremental addressing; wave may start mid-row: w6 init = hwBase%6.
  int w6 = hwBase % 6;
  int pb = (hwBase / 6) * 256 + w6 * 32 + tl0;   // padT offset of window origin
  int sbase = hwBase * 32 + tl0;                 // statT offset
  const float* refsrc = refdata + (size_t)(hwBase + 1) * 1152;

#pragma unroll 1
  for (int it = 0; it < 8; ++it) {
    const float* buf = rbuf + (it & 1) * 1152;

    if (it < 7) {
      // Restaged buffer's last ds_reads were consumed in it-1 (data already
      // in VGPRs) -> WAR-safe without lgkm fence. Counted vmcnt: this px's
      // 6 loads complete, next px's 6 stay in flight.
      stage_px(refsrc, rbuf + ((it + 1) & 1) * 1152, lane);
      asm volatile("s_waitcnt vmcnt(6)" ::: "memory");
    } else {
      asm volatile("s_waitcnt vmcnt(0)" ::: "memory");
    }
    refsrc += 1152;

    // Tile window pixels: 9 taps x 8 tiles (18 x ds_read_b128)
    float tp[9][8];
#pragma unroll
    for (int ik = 0; ik < 3; ++ik)
#pragma unroll
      for (int jk = 0; jk < 3; ++jk) {
        const int k = ik * 3 + jk;
        const float4 a = *(const float4*)&padT[pb + (ik * 8 + jk) * 32];
        const float4 b = *(const float4*)&padT[pb + (ik * 8 + jk) * 32 + 4];
        tp[k][0] = a.x; tp[k][1] = a.y; tp[k][2] = a.z; tp[k][3] = a.w;
        tp[k][4] = b.x; tp[k][5] = b.y; tp[k][6] = b.z; tp[k][7] = b.w;
      }

    // tile stats (8 tiles): mu, sig
    float mu[8], sg[8], mt2[8];
    {
      float4 v;
      v = *(const float4*)&statT[sbase];            mu[0]=v.x; mu[1]=v.y; mu[2]=v.z; mu[3]=v.w;
      v = *(const float4*)&statT[sbase + 4];        mu[4]=v.x; mu[5]=v.y; mu[6]=v.z; mu[7]=v.w;
      v = *(const float4*)&statT[3072 + sbase];     sg[0]=v.x; sg[1]=v.y; sg[2]=v.z; sg[3]=v.w;
      v = *(const float4*)&statT[3072 + sbase + 4]; sg[4]=v.x; sg[5]=v.y; sg[6]=v.z; sg[7]=v.w;
#pragma unroll
      for (int i = 0; i < 8; ++i) mt2[i] = mu[i] * mu[i];
    }

#pragma unroll
    for (int j = 0; j < 6; ++j) {
      const int rb = (rthr + 16 * j) * 12;
      const float4 wa = *(const float4*)&buf[rb];
      const float4 wb = *(const float4*)&buf[rb + 4];
      const float4 wc = *(const float4*)&buf[rb + 8];
#pragma unroll
      for (int i = 0; i < 8; ++i) {
        float ev = fmaf(tp[0][i], wa.x, kC2);
        ev = fmaf(tp[1][i], wa.y, ev);
        ev = fmaf(tp[2][i], wa.z, ev);
        ev = fmaf(tp[3][i], wa.w, ev);
        ev = fmaf(tp[4][i], wb.x, ev);
        ev = fmaf(tp[5][i], wb.y, ev);
        ev = fmaf(tp[6][i], wb.z, ev);
        ev = fmaf(tp[7][i], wb.w, ev);
        ev = fmaf(tp[8][i], wc.x, ev);
        // wc.y = 2*mu_r, wc.z = mu_r^2+C1, wc.w = sig_r+C2
        const float am = mu[i] * wc.y;             // 2*mt*mr
        const float n1 = am + kC1;
        const float n2 = ev - am;                  // 2*sig_tr + C2
        const float d1 = mt2[i] + wc.z;            // mt^2+mr^2+C1
        const float d2 = sg[i] + wc.w;
        const float nn = n1 * n2;
        const float dd = d1 * d2;
        // raw v_rcp_f32: ~1-ulp (passed absmax 0 in R8).
        const float r0v = __builtin_amdgcn_rcpf(dd);
        score[i][j] = fmaf(nn, r0v, score[i][j]);
      }
    }

    pb += (w6 == 5) ? 96 : 32;       // col step 32; row wrap: +3 window cols
    w6 = (w6 == 5) ? 0 : w6 + 1;
    sbase += 32;
  }

  // sb overlay: all waves done with padT/statT/refbuf
  __syncthreads();
  float* sb = smem;   // [12][32][97]
#pragma unroll
  for (int i = 0; i < 8; ++i)
#pragma unroll
    for (int j = 0; j < 6; ++j)
      sb[w * 3104 + (tl0 + i) * 97 + (rthr * 6 + j)] = score[i][j];
  __syncthreads();

  // Reduce 12 wave-partials + density penalty + per-tile argmax (95 refs)
  if (tid < 512) {
    const int tile = tid >> 4, rt = tid & 15;
    const float dt = densT[tile];
    float best = -1e30f; int bi = 0;
#pragma unroll
    for (int q = 0; q < 6; ++q) {
      const int r = rt * 6 + q;
      if (r < 95) {
        float s = 0.f;
#pragma unroll
        for (int g = 0; g < 12; ++g) s += sb[g * 3104 + tile * 97 + r];
        s = s * (1.0f / 96.0f) - 3.0f * fabsf(dt - densR[r]);
        if (s > best) { best = s; bi = r; }   // ascending r, strict >
      }
    }
#pragma unroll
    for (int m = 8; m >= 1; m >>= 1) {
      const float ob = __shfl_xor(best, m, 64);
      const int oi = __shfl_xor(bi, m, 64);
      if (ob > best || (ob == best && oi < bi)) { best = ob; bi = oi; }
    }
    if (rt == 0) out[row0 * 128 + c0 + tile] = bi;
  }
}

// ---------------- Host launch ----------------
extern "C" void kernel_launch(void* const* d_in, const int* in_sizes, int n_in,
                              void* d_out, int out_size, void* d_ws, size_t ws_size,
                              hipStream_t stream) {
  (void)in_sizes; (void)n_in; (void)out_size; (void)ws_size;
  const float* img = (const float*)d_in[0];
  const float* chars = (const float*)d_in[1];
  int* out = (int*)d_out;
  float* refdata = (float*)d_ws;                  // 96*96*12 = 110592 floats
  float* densR = refdata + 110592;                // +96

  KF kf;
  {
    float gg[3], s = 0.f;
    for (int i = 0; i < 3; ++i) {
      const float c = (float)i - 1.0f;
      gg[i] = expf(-(c * c) / (2.0f * 1.5f * 1.5f));
      s += gg[i];
    }
    float gn[3];
    for (int i = 0; i < 3; ++i) gn[i] = gg[i] / s;
    float k2[9]; float ks = 0.f;
    for (int i = 0; i < 3; ++i)
      for (int j = 0; j < 3; ++j) { k2[i * 3 + j] = gn[i] * gn[j]; ks += k2[i * 3 + j]; }
    for (int k = 0; k < 9; ++k) kf.k[k] = k2[k] / ks;
  }

  hipLaunchKernelGGL(refprep_kernel, dim3(96), dim3(128), 0, stream,
                     chars, refdata, densR, kf);
  hipLaunchKernelGGL(ssim_main_kernel, dim3(256), dim3(768), 0, stream,
                     img, refdata, densR, out, kf);
}

// Round 10
// 60.914 us; speedup vs baseline: 2.1628x; 2.1628x over previous
//
#include <hip/hip_runtime.h>
#include <math.h>

// SSIM char-matcher: img (1,1,1024,768) f32, chars (95,1,16,6) f32 -> argmax idx [64][128] int32
// H=16, W=6, WIN=3, tiles T=8192 (64 rows x 128 cols), refs R=95 (pad to 96)
// Grid: 256 blocks = (64 rows) x (4 col-groups of 32 tiles); all 96 refs in-block.
// 512 threads = 8 waves = 4 PAIRS. Pair p owns px [24p,24p+24); the two waves of a
// pair split the 32 tiles (16 each) and SHARE one double-buffered ref chunk.
// LDS 79.9 KB -> 2 blocks/CU -> 4 waves/SIMD (R7 was 2: latency-bound at 55% duty).

static constexpr float kC1 = 1.0e-4f;   // 0.01^2
static constexpr float kC2 = 9.0e-4f;   // 0.03^2

struct KF { float k[9]; };

__device__ __forceinline__ int refl(int x, int n) {
  if (x < 0) return -x;
  if (x >= n) return 2 * n - 2 - x;
  return x;
}

// ---------------- Kernel 1: per-ref precompute ----------------
// refdata: per hw a chunk of 96 rows x 12 floats (4608 B, contiguous).
// Logical ref r (0..95) stored at physical row rp = r/6 + 16*(r%6)
// (lane rthr reads ref rthr*6+j at row rthr+16j -> stride 48 B, 2-way banks = ~free).
// Row: f0..8 = 2*k[k]*Rp[k] (DOUBLED), f9 = 2*mu_r (DOUBLED),
// f10 = mu_r^2 + C1, f11 = sig_r + C2.  r=95 is padding (never argmax'd).
__global__ __launch_bounds__(128) void refprep_kernel(
    const float* __restrict__ chars, float* __restrict__ refdata,
    float* __restrict__ densR, KF kf) {
  const int hw = blockIdx.x;   // 0..95
  const int r = threadIdx.x;   // 0..127
  if (r >= 96) return;
  const int rp = r / 6 + 16 * (r % 6);
  float* row = refdata + ((size_t)hw * 96 + rp) * 12;
  const int h = hw / 6, w = hw % 6;
  if (r < 95) {
    const float* cb = chars + r * 96;
    float mu = 0.f, ex2 = 0.f;
    float wrv[9];
#pragma unroll
    for (int i = 0; i < 3; ++i) {
      const int hh = refl(h + i - 1, 16);
#pragma unroll
      for (int j = 0; j < 3; ++j) {
        const int ww = refl(w + j - 1, 6);
        const float p = cb[hh * 6 + ww];
        const float kv = kf.k[i * 3 + j];
        wrv[i * 3 + j] = 2.0f * kv * p;
        mu += kv * p;
        ex2 += kv * p * p;
      }
    }
    const float sig = ex2 - mu * mu;
#pragma unroll
    for (int k = 0; k < 9; ++k) row[k] = wrv[k];
    row[9]  = 2.0f * mu;
    row[10] = mu * mu + kC1;
    row[11] = sig + kC2;
  } else {
#pragma unroll
    for (int k = 0; k < 9; ++k) row[k] = 0.f;
    row[9]  = 0.f;
    row[10] = kC1;
    row[11] = kC2;
  }
  if (hw == 0) {
    if (r < 95) {
      float s = 0.f;
      for (int i = 0; i < 96; ++i) s += chars[r * 96 + i];
      densR[r] = s * (1.0f / 96.0f);
    } else {
      densR[r] = 0.f;
    }
  }
}

// ---- async global->LDS staging: HALF of one 4608 B ref chunk per wave ----
// Wave `half` covers bytes [half*2304, half*2304+2304): 2 x (64x16B) + 1 x (64x4B).
// The per-px __syncthreads (compiler drains vmcnt(0) before s_barrier) is the
// completion/ordering sync — no manual s_waitcnt needed.
__device__ __forceinline__ void stage_half(const float* __restrict__ src,
                                           float* dst, int lane, int half) {
  const uintptr_t gs = (uintptr_t)src + half * 2304;
  const uintptr_t ls = (uintptr_t)dst + half * 2304;
#define G_(off) ((const __attribute__((address_space(1))) void*)(gs + (off)))
#define L_(off) ((__attribute__((address_space(3))) void*)(uint32_t)(ls + (off)))
  __builtin_amdgcn_global_load_lds(G_(0    + lane * 16), L_(0),    16, 0, 0);
  __builtin_amdgcn_global_load_lds(G_(1024 + lane * 16), L_(1024), 16, 0, 0);
  __builtin_amdgcn_global_load_lds(G_(2048 + lane * 4),  L_(2048), 4, 0, 0);
#undef G_
#undef L_
}

// ---------------- Kernel 2: main SSIM + argmax ----------------
// 256 blocks x 512 threads (8 waves = 4 pairs). Pair p: px [24p,24p+24),
// double-buffered shared chunk; wave half h: tiles [16h,16h+16).
// lane = tthr(4 x 4 tiles) x rthr(16 x 6 refs) -> 24 el/thread.
// Per px: stage next chunk (split across the pair, 3 loads/wave) BEFORE
// compute, then one __syncthreads: the barrier's vmcnt(0)+lgkmcnt(0) drain
// is the staging sync AND the WAR fence for the shared buffer. 24 barriers
// per block; 2 blocks/CU cover each other's barrier stalls.
// __launch_bounds__(512,2): the only spelling that avoids the 64-VGPR
// squeeze (R2/R7: 128 VGPR, no spills; R3-R5/R8-R9 all other spellings
// squeezed+spilled). Pressure ~100 -> alloc <=128 -> 4 waves/SIMD.
__global__ __launch_bounds__(512, 2)
void ssim_main_kernel(
    const float* __restrict__ img, const float* __restrict__ refdata,
    const float* __restrict__ densR, int* __restrict__ out, KF kf) {
  // [0:4608) padT [144][32] | [4608:10752) statT [2][96][32] |
  // [10752:19968) refbuf 4 pairs x 2 x 1152 = 79.9 KB total -> 2 blocks/CU.
  // Overlay after main loop: sb[4][32][97] = 12416 floats.
  __shared__ float smem[19968];
  __shared__ float densT[32];
  float* padT = smem;
  float* statT = smem + 4608;

  const int tid = threadIdx.x;
  const int w = tid >> 6;          // wave 0..7
  const int p = w >> 1;            // pair 0..3
  const int half = w & 1;          // tile-half within pair
  const int lane = tid & 63;
  const int tthr = lane >> 4;      // 0..3  -> 4 tiles each
  const int rthr = lane & 15;      // 0..15 -> 6 refs each
  const int tl0 = half * 16 + tthr * 4;
  const int blk = blockIdx.x;
  const int row0 = blk >> 2;           // tile-row 0..63
  const int c0 = (blk & 3) * 32;       // tile-col base
  const int hwBase = p * 24;           // pair = 4 full px-rows
  float* pairbuf = smem + 10752 + p * 2304;   // pair-shared 2 x 1152

  // Prologue: stage px0 into slot 0 (both waves of the pair stage their half).
  stage_half(refdata + (size_t)hwBase * 1152, pairbuf, lane, half);

  // Phase A: reflect-padded tiles, transposed: padT[c(0..143)][tile(0..31)]
  for (int idx = tid; idx < 4608; idx += 512) {
    const int c = idx >> 5, tl = idx & 31;
    const int ph = c >> 3, pw = c & 7;
    const int h = refl(ph - 1, 16), ww = refl(pw - 1, 6);
    padT[idx] = img[(row0 * 16 + h) * 768 + (c0 + tl) * 6 + ww];
  }
  __syncthreads();

  if (tid < 32) {
    float s = 0.f;
    for (int h = 0; h < 16; ++h)
      for (int ww = 0; ww < 6; ++ww)
        s += padT[((h + 1) * 8 + (ww + 1)) * 32 + tid];
    densT[tid] = s * (1.0f / 96.0f);
  }
  // Phase B: per-(hw, tile) stats: mu, sig
  for (int idx = tid; idx < 3072; idx += 512) {
    const int hw = idx >> 5, tl = idx & 31;
    const int h = hw / 6, ww = hw % 6;
    float mu = 0.f, ex2 = 0.f;
#pragma unroll
    for (int i = 0; i < 3; ++i)
#pragma unroll
      for (int j = 0; j < 3; ++j) {
        const float p2 = padT[((h + i) * 8 + (ww + j)) * 32 + tl];
        const float kv = kf.k[i * 3 + j];
        mu += kv * p2;
        ex2 += kv * p2 * p2;
      }
    statT[idx] = mu;
    statT[3072 + idx] = ex2 - mu * mu;
  }
  __syncthreads();   // drains prologue staging too (vmcnt(0) before s_barrier)

  float score[4][6];
#pragma unroll
  for (int i = 0; i < 4; ++i)
#pragma unroll
    for (int j = 0; j < 6; ++j) score[i][j] = 0.f;

  // Incremental addressing; hwBase % 6 == 0: w6 cycles 0..5 four times.
  int w6 = 0;
  int pb = (hwBase / 6) * 256 + tl0;   // padT offset of window origin
  int sbase = hwBase * 32 + tl0;       // statT offset
  const float* refsrc = refdata + (size_t)(hwBase + 1) * 1152;
  int slot = 0;

#pragma unroll 1
  for (int it = 0; it < 24; ++it) {
    const float* buf = pairbuf + slot * 1152;

    // Issue next px's staging first: ~1000 cyc of compute below hides it.
    if (it < 23) {
      stage_half(refsrc, pairbuf + (slot ^ 1) * 1152, lane, half);
      refsrc += 1152;
    }

    // Tile window pixels: 9 taps x 4 tiles (9 x ds_read_b128)
    float tp[9][4];
#pragma unroll
    for (int ik = 0; ik < 3; ++ik)
#pragma unroll
      for (int jk = 0; jk < 3; ++jk) {
        const int k = ik * 3 + jk;
        const float4 a = *(const float4*)&padT[pb + (ik * 8 + jk) * 32];
        tp[k][0] = a.x; tp[k][1] = a.y; tp[k][2] = a.z; tp[k][3] = a.w;
      }

    // tile stats (4 tiles): mu, sig
    float mu[4], sg[4], mt2[4];
    {
      const float4 m = *(const float4*)&statT[sbase];
      const float4 s = *(const float4*)&statT[3072 + sbase];
      mu[0]=m.x; mu[1]=m.y; mu[2]=m.z; mu[3]=m.w;
      sg[0]=s.x; sg[1]=s.y; sg[2]=s.z; sg[3]=s.w;
#pragma unroll
      for (int i = 0; i < 4; ++i) mt2[i] = mu[i] * mu[i];
    }

#pragma unroll
    for (int j = 0; j < 6; ++j) {
      const int rb = (rthr + 16 * j) * 12;
      const float4 wa = *(const float4*)&buf[rb];
      const float4 wb = *(const float4*)&buf[rb + 4];
      const float4 wc = *(const float4*)&buf[rb + 8];
#pragma unroll
      for (int i = 0; i < 4; ++i) {
        float ev = fmaf(tp[0][i], wa.x, kC2);
        ev = fmaf(tp[1][i], wa.y, ev);
        ev = fmaf(tp[2][i], wa.z, ev);
        ev = fmaf(tp[3][i], wa.w, ev);
        ev = fmaf(tp[4][i], wb.x, ev);
        ev = fmaf(tp[5][i], wb.y, ev);
        ev = fmaf(tp[6][i], wb.z, ev);
        ev = fmaf(tp[7][i], wb.w, ev);
        ev = fmaf(tp[8][i], wc.x, ev);
        // wc.y = 2*mu_r, wc.z = mu_r^2+C1, wc.w = sig_r+C2
        const float am = mu[i] * wc.y;             // 2*mt*mr
        const float n1 = am + kC1;
        const float n2 = ev - am;                  // 2*sig_tr + C2
        const float d1 = mt2[i] + wc.z;            // mt^2+mr^2+C1
        const float d2 = sg[i] + wc.w;
        const float nn = n1 * n2;
        const float dd = d1 * d2;
        // raw v_rcp_f32: ~1-ulp (passed absmax 0 in R8/R9).
        const float r0v = __builtin_amdgcn_rcpf(dd);
        score[i][j] = fmaf(nn, r0v, score[i][j]);
      }
    }

    // Barrier: (a) next-px staging complete (vmcnt drain), (b) WAR fence for
    // the pair-shared buffer, (c) keeps pairs in lockstep. One per px.
    __syncthreads();

    pb += (w6 == 5) ? 96 : 32;       // col step 32; row wrap: +3 window cols
    w6 = (w6 == 5) ? 0 : w6 + 1;
    sbase += 32;
    slot ^= 1;
  }

  // sb overlay (padT/statT/refbuf dead): sb[4 pairs][32][97]
  float* sb = smem;
#pragma unroll
  for (int i = 0; i < 4; ++i)
#pragma unroll
    for (int j = 0; j < 6; ++j)
      sb[p * 3104 + (tl0 + i) * 97 + (rthr * 6 + j)] = score[i][j];
  __syncthreads();

  // Reduce 4 pair-partials + density penalty + per-tile argmax (95 refs)
  {
    const int tile = tid >> 4, rt = tid & 15;
    const float dt = densT[tile];
    float best = -1e30f; int bi = 0;
#pragma unroll
    for (int q = 0; q < 6; ++q) {
      const int r = rt * 6 + q;
      if (r < 95) {
        float s = 0.f;
#pragma unroll
        for (int g = 0; g < 4; ++g) s += sb[g * 3104 + tile * 97 + r];
        s = s * (1.0f / 96.0f) - 3.0f * fabsf(dt - densR[r]);
        if (s > best) { best = s; bi = r; }   // ascending r, strict >
      }
    }
#pragma unroll
    for (int m = 8; m >= 1; m >>= 1) {
      const float ob = __shfl_xor(best, m, 64);
      const int oi = __shfl_xor(bi, m, 64);
      if (ob > best || (ob == best && oi < bi)) { best = ob; bi = oi; }
    }
    if (rt == 0) out[row0 * 128 + c0 + tile] = bi;
  }
}

// ---------------- Host launch ----------------
extern "C" void kernel_launch(void* const* d_in, const int* in_sizes, int n_in,
                              void* d_out, int out_size, void* d_ws, size_t ws_size,
                              hipStream_t stream) {
  (void)in_sizes; (void)n_in; (void)out_size; (void)ws_size;
  const float* img = (const float*)d_in[0];
  const float* chars = (const float*)d_in[1];
  int* out = (int*)d_out;
  float* refdata = (float*)d_ws;                  // 96*96*12 = 110592 floats
  float* densR = refdata + 110592;                // +96

  KF kf;
  {
    float gg[3], s = 0.f;
    for (int i = 0; i < 3; ++i) {
      const float c = (float)i - 1.0f;
      gg[i] = expf(-(c * c) / (2.0f * 1.5f * 1.5f));
      s += gg[i];
    }
    float gn[3];
    for (int i = 0; i < 3; ++i) gn[i] = gg[i] / s;
    float k2[9]; float ks = 0.f;
    for (int i = 0; i < 3; ++i)
      for (int j = 0; j < 3; ++j) { k2[i * 3 + j] = gn[i] * gn[j]; ks += k2[i * 3 + j]; }
    for (int k = 0; k < 9; ++k) kf.k[k] = k2[k] / ks;
  }

  hipLaunchKernelGGL(refprep_kernel, dim3(96), dim3(128), 0, stream,
                     chars, refdata, densR, kf);
  hipLaunchKernelGGL(ssim_main_kernel, dim3(256), dim3(512), 0, stream,
                     img, refdata, densR, out, kf);
}